// Round 4
// baseline (351.472 us; speedup 1.0000x reference)
//
#include <hip/hip_runtime.h>

// Problem constants (from reference setup_inputs):
// attention: [B=64, L=12, H=12, Q=1, S=8192] float32
// out: concat(p [64,8192], logits [64,8192]) float32
#define BATCH 64
#define NLAYER 12
#define NHEAD 12
#define SEQ 8192
#define NTHREADS 1024
#define EPT 8  // elements per thread = SEQ / NTHREADS

__global__ __launch_bounds__(NTHREADS)
void entmax15_kernel(const float* __restrict__ att, float* __restrict__ out) {
    const int b = blockIdx.x;
    const int t = threadIdx.x;
    const int wave = t >> 6;
    const int lane = t & 63;

    // Base of attention[b, L-1, :, 0, :]  (contiguous H*S block)
    const float* base = att + ((size_t)b * NLAYER + (NLAYER - 1)) * ((size_t)NHEAD * SEQ);

    // ---- mean over heads: 8 elements per thread, float4 loads ----
    float v[EPT];
#pragma unroll
    for (int i = 0; i < EPT; ++i) v[i] = 0.0f;

#pragma unroll
    for (int h = 0; h < NHEAD; ++h) {
        const float4* p4 = reinterpret_cast<const float4*>(base + (size_t)h * SEQ + (size_t)t * EPT);
        float4 a = p4[0];
        float4 c = p4[1];
        v[0] += a.x; v[1] += a.y; v[2] += a.z; v[3] += a.w;
        v[4] += c.x; v[5] += c.y; v[6] += c.z; v[7] += c.w;
    }
    const float inv_h = 1.0f / (float)NHEAD;
#pragma unroll
    for (int i = 0; i < EPT; ++i) v[i] *= inv_h;

    // ---- store logits (second output, offset BATCH*SEQ) ----
    {
        float* lg = out + (size_t)BATCH * SEQ + (size_t)b * SEQ + (size_t)t * EPT;
        float4 o0 = make_float4(v[0], v[1], v[2], v[3]);
        float4 o1 = make_float4(v[4], v[5], v[6], v[7]);
        reinterpret_cast<float4*>(lg)[0] = o0;
        reinterpret_cast<float4*>(lg)[1] = o1;
    }

    // ---- z = logits/2, subtract row max ----
    float z[EPT];
#pragma unroll
    for (int i = 0; i < EPT; ++i) z[i] = v[i] * 0.5f;

    float m = z[0];
#pragma unroll
    for (int i = 1; i < EPT; ++i) m = fmaxf(m, z[i]);
    // wave (64-lane) max reduce
    for (int off = 32; off > 0; off >>= 1) m = fmaxf(m, __shfl_down(m, off));

    __shared__ float s_red[16];
    __shared__ float s_bcast;
    if (lane == 0) s_red[wave] = m;
    __syncthreads();
    if (t == 0) {
        float mm = s_red[0];
#pragma unroll
        for (int w = 1; w < NTHREADS / 64; ++w) mm = fmaxf(mm, s_red[w]);
        s_bcast = mm;
    }
    __syncthreads();
    m = s_bcast;
#pragma unroll
    for (int i = 0; i < EPT; ++i) z[i] -= m;

    // ---- bisection for tau in [-1, 0]:  f(tau) = sum((z - tau)_+^2) = 1 ----
    float lo = -1.0f, hi = 0.0f;
    for (int iter = 0; iter < 32; ++iter) {
        const float tau = 0.5f * (lo + hi);
        float s = 0.0f;
#pragma unroll
        for (int i = 0; i < EPT; ++i) {
            float d = fmaxf(z[i] - tau, 0.0f);
            s = fmaf(d, d, s);
        }
        for (int off = 32; off > 0; off >>= 1) s += __shfl_down(s, off);
        if (lane == 0) s_red[wave] = s;
        __syncthreads();
        if (t == 0) {
            float tot = 0.0f;
#pragma unroll
            for (int w = 0; w < NTHREADS / 64; ++w) tot += s_red[w];
            s_bcast = tot;
        }
        __syncthreads();
        const float tot = s_bcast;  // uniform across block
        if (tot >= 1.0f) lo = tau; else hi = tau;
        __syncthreads();  // protect s_red/s_bcast before next iteration's writes
    }
    const float tau = 0.5f * (lo + hi);

    // ---- p = ((z - tau)_+)^2 (first output) ----
    float p[EPT];
#pragma unroll
    for (int i = 0; i < EPT; ++i) {
        float d = fmaxf(z[i] - tau, 0.0f);
        p[i] = d * d;
    }
    float* pd = out + (size_t)b * SEQ + (size_t)t * EPT;
    float4 q0 = make_float4(p[0], p[1], p[2], p[3]);
    float4 q1 = make_float4(p[4], p[5], p[6], p[7]);
    reinterpret_cast<float4*>(pd)[0] = q0;
    reinterpret_cast<float4*>(pd)[1] = q1;
}

extern "C" void kernel_launch(void* const* d_in, const int* in_sizes, int n_in,
                              void* d_out, int out_size, void* d_ws, size_t ws_size,
                              hipStream_t stream) {
    const float* att = (const float*)d_in[0];
    float* out = (float*)d_out;
    entmax15_kernel<<<BATCH, NTHREADS, 0, stream>>>(att, out);
}

// Round 5
// 337.917 us; speedup vs baseline: 1.0401x; 1.0401x over previous
//
#include <hip/hip_runtime.h>

// attention: [B=64, L=12, H=12, Q=1, S=8192] float32
// out: concat(p [64,8192], logits [64,8192]) float32
#define BATCH 64
#define NLAYER 12
#define NHEAD 12
#define SEQ 8192

// ---------------- Kernel 1: logits = mean over heads (full-chip BW) --------
// 512 blocks x 256 threads; each block does 1024 cols of one batch row.
#define K1_THREADS 256
#define K1_CHUNK 1024
__global__ __launch_bounds__(K1_THREADS)
void mean_kernel(const float* __restrict__ att, float* __restrict__ out) {
    const int blk = blockIdx.x;
    const int b = blk >> 3;        // 8 chunks per row
    const int c = blk & 7;
    const int col = c * K1_CHUNK + threadIdx.x * 4;
    const float* base = att
        + ((size_t)b * NLAYER + (NLAYER - 1)) * ((size_t)NHEAD * SEQ) + col;
    float4 acc = make_float4(0.f, 0.f, 0.f, 0.f);
#pragma unroll
    for (int h = 0; h < NHEAD; ++h) {
        float4 a = *reinterpret_cast<const float4*>(base + (size_t)h * SEQ);
        acc.x += a.x; acc.y += a.y; acc.z += a.z; acc.w += a.w;
    }
    const float s = 1.0f / (float)NHEAD;
    acc.x *= s; acc.y *= s; acc.z *= s; acc.w *= s;
    *reinterpret_cast<float4*>(out + (size_t)BATCH * SEQ + (size_t)b * SEQ + col) = acc;
}

// ---------------- Kernel 2: 1.5-entmax per row via tau bisection -----------
#define K2_THREADS 1024
#define EPT 8                    // SEQ / K2_THREADS
#define NWAVES (K2_THREADS / 64)
#define NITER 16                 // dtau = 2^-16; p error <= 2*dtau << 2.8e-2
__global__ __launch_bounds__(K2_THREADS)
void entmax_kernel(float* __restrict__ out) {
    const int b = blockIdx.x;
    const int t = threadIdx.x;
    const int wave = t >> 6;
    const int lane = t & 63;

    // read logits (just written by mean_kernel; L2/LLC resident)
    const float* lg = out + (size_t)BATCH * SEQ + (size_t)b * SEQ + (size_t)t * EPT;
    float z[EPT];
    {
        float4 a0 = reinterpret_cast<const float4*>(lg)[0];
        float4 a1 = reinterpret_cast<const float4*>(lg)[1];
        z[0] = a0.x; z[1] = a0.y; z[2] = a0.z; z[3] = a0.w;
        z[4] = a1.x; z[5] = a1.y; z[6] = a1.z; z[7] = a1.w;
    }
#pragma unroll
    for (int i = 0; i < EPT; ++i) z[i] *= 0.5f;

    // ---- block max: wave shuffle reduce -> LDS -> every thread folds 16 ----
    __shared__ float s_m[NWAVES];
    __shared__ float s_s[2][NWAVES];

    float m = z[0];
#pragma unroll
    for (int i = 1; i < EPT; ++i) m = fmaxf(m, z[i]);
#pragma unroll
    for (int off = 32; off > 0; off >>= 1) m = fmaxf(m, __shfl_down(m, off));
    if (lane == 0) s_m[wave] = m;
    __syncthreads();
    m = s_m[0];
#pragma unroll
    for (int w = 1; w < NWAVES; ++w) m = fmaxf(m, s_m[w]);
#pragma unroll
    for (int i = 0; i < EPT; ++i) z[i] -= m;

    // ---- bisection: f(tau) = sum((z-tau)_+^2) = 1, tau in [-1, 0] ----
    // double-buffered LDS partials: exactly 1 barrier per iteration
    float lo = -1.0f, hi = 0.0f;
#pragma unroll 1
    for (int iter = 0; iter < NITER; ++iter) {
        const int buf = iter & 1;
        const float tau = 0.5f * (lo + hi);
        float s = 0.0f;
#pragma unroll
        for (int i = 0; i < EPT; ++i) {
            float d = fmaxf(z[i] - tau, 0.0f);
            s = fmaf(d, d, s);
        }
#pragma unroll
        for (int off = 32; off > 0; off >>= 1) s += __shfl_down(s, off);
        if (lane == 0) s_s[buf][wave] = s;
        __syncthreads();
        float tot = 0.0f;
#pragma unroll
        for (int w = 0; w < NWAVES; ++w) tot += s_s[buf][w];
        if (tot >= 1.0f) lo = tau; else hi = tau;
        // next iteration writes the OTHER buffer -> no WAR hazard, no barrier
    }
    const float tau = 0.5f * (lo + hi);

    // ---- p = ((z - tau)_+)^2 ----
    float p[EPT];
#pragma unroll
    for (int i = 0; i < EPT; ++i) {
        float d = fmaxf(z[i] - tau, 0.0f);
        p[i] = d * d;
    }
    float* pd = out + (size_t)b * SEQ + (size_t)t * EPT;
    reinterpret_cast<float4*>(pd)[0] = make_float4(p[0], p[1], p[2], p[3]);
    reinterpret_cast<float4*>(pd)[1] = make_float4(p[4], p[5], p[6], p[7]);
}

extern "C" void kernel_launch(void* const* d_in, const int* in_sizes, int n_in,
                              void* d_out, int out_size, void* d_ws, size_t ws_size,
                              hipStream_t stream) {
    const float* att = (const float*)d_in[0];
    float* out = (float*)d_out;
    mean_kernel<<<BATCH * 8, K1_THREADS, 0, stream>>>(att, out);
    entmax_kernel<<<BATCH, K2_THREADS, 0, stream>>>(out);
}